// Round 2
// baseline (7217.000 us; speedup 1.0000x reference)
//
#include <hip/hip_runtime.h>

// ---------------------------------------------------------------------------
// STLT forward, bf16-activation / f32-compute, low-memory (<123 MB scratch).
// Layout: activations flat (65536, 256) rows = (b, i, j); groups (b,i), the
// attention axis is j (last). T==S==64 makes qt==qs and kt==ks, so the concat
// in _st_attn folds: Weff = Wo[:, :256] + Wo[:, 256:].
// ---------------------------------------------------------------------------

typedef unsigned short u16;

__device__ __forceinline__ float b2f(u16 u) {
  union { float f; unsigned int i; } v; v.i = ((unsigned int)u) << 16; return v.f;
}
__device__ __forceinline__ u16 f2b(float f) {
  union { float f; unsigned int i; } v; v.f = f;
  unsigned int x = v.i;
  return (u16)((x + 0x7FFFu + ((x >> 16) & 1u)) >> 16);
}

// ---------------- diagnostics --------------------------------------------
__global__ void ws_signal(float* out, float v) { out[0] = v; }

// ---------------- positional encoding: pe[64][256] -----------------------
__global__ void pe_kernel(float* __restrict__ pe) {
  int l = blockIdx.x, d = threadIdx.x;
  int i = d >> 1;
  float div = expf((float)(2 * i) * (-9.210340371976184f / 256.0f));
  float ang = (float)l * div;
  pe[l * 256 + d] = (d & 1) ? cosf(ang) : sinf(ang);
}

// ---------------- embedding convs (circular, K=3), f32 -------------------
__global__ void conv_sproj(const float* __restrict__ x, const float* __restrict__ w,
                           const float* __restrict__ bias, float* __restrict__ h1) {
  int o = blockIdx.x, b = blockIdx.y, l = threadIdx.x;  // l < 96
  const float* wo = w + o * 192;
  const float* xb = x + (size_t)b * 96 * 64;
  float acc = bias[o];
#pragma unroll
  for (int k = 0; k < 3; ++k) {
    int lp = l + k - 1; if (lp < 0) lp += 96; if (lp >= 96) lp -= 96;
    const float* xr = xb + lp * 64;
    for (int c = 0; c < 64; ++c) acc = fmaf(xr[c], wo[c * 3 + k], acc);
  }
  h1[((size_t)b * 96 + o) * 96 + l] = acc;
}

__global__ void conv_scproj_t(const float* __restrict__ h1, const float* __restrict__ w,
                              const float* __restrict__ bias, float* __restrict__ h2) {
  int o = blockIdx.x, b = blockIdx.y, l = threadIdx.x;  // o<64, l<96
  const float* wo = w + o * 288;
  const float* hb = h1 + (size_t)b * 96 * 96;
  float acc = bias[o];
#pragma unroll
  for (int k = 0; k < 3; ++k) {
    int lp = l + k - 1; if (lp < 0) lp += 96; if (lp >= 96) lp -= 96;
    for (int c = 0; c < 96; ++c) acc = fmaf(hb[c * 96 + lp], wo[c * 3 + k], acc);
  }
  h2[((size_t)b * 64 + o) * 96 + l] = acc;
}

__global__ void conv_scproj_s(const float* __restrict__ h2, const float* __restrict__ w,
                              const float* __restrict__ bias, float* __restrict__ h3) {
  int o = blockIdx.x, b = blockIdx.y, l = threadIdx.x;  // o<64, l<64
  const float* wo = w + o * 288;
  const float* hb = h2 + (size_t)b * 64 * 96;
  float acc = bias[o];
#pragma unroll
  for (int k = 0; k < 3; ++k) {
    int lp = l + k - 1; if (lp < 0) lp += 64; if (lp >= 64) lp -= 64;
    for (int c = 0; c < 96; ++c) acc = fmaf(hb[lp * 96 + c], wo[c * 3 + k], acc);
  }
  h3[((size_t)b * 64 + o) * 64 + l] = acc;
}

// tok conv (in-ch=1) + PE -> bf16 activation
__global__ void tok_embed(const float* __restrict__ h3, const float* __restrict__ w,
                          const float* __restrict__ bias, const float* __restrict__ pe,
                          u16* __restrict__ E) {
  int g = blockIdx.x;   // 0..1023
  int d = threadIdx.x;  // 0..255
  __shared__ float row[64];
  if (d < 64) row[d] = h3[(size_t)g * 64 + d];
  __syncthreads();
  float w0 = w[d * 3], w1 = w[d * 3 + 1], w2 = w[d * 3 + 2], bd = bias[d];
  for (int j = 0; j < 64; ++j) {
    int jm = (j + 63) & 63, jp = (j + 1) & 63;
    float v = bd + row[jm] * w0 + row[j] * w1 + row[jp] * w2 + pe[j * 256 + d];
    E[((size_t)g * 64 + j) * 256 + d] = f2b(v);
  }
}

// ---------------- GEMM: C(M,N) bf16 = A(M,K) bf16 @ W(N,K)^T f32 + bias ---
// 64x64 tile, BK=16, 256 threads, 4x4 acc. ACT: 0=none, 1=exact GELU.
template <int ACT>
__global__ __launch_bounds__(256) void gemm_bf16(const u16* __restrict__ A,
                                                 const float* __restrict__ W,
                                                 const float* __restrict__ bias,
                                                 u16* __restrict__ C, int N, int K) {
  __shared__ float As[16][68];
  __shared__ float Ws[16][68];
  int t = threadIdx.x;
  int row0 = blockIdx.y * 64, col0 = blockIdx.x * 64;
  int tx = t & 15, ty = t >> 4;
  int lr = t >> 2, lc = (t & 3) << 2;
  const u16* Ap = A + (size_t)(row0 + lr) * K + lc;
  const float* Wp = W + (size_t)(col0 + lr) * K + lc;
  float acc[4][4] = {};
  for (int k0 = 0; k0 < K; k0 += 16) {
    ushort4 a = *(const ushort4*)(Ap + k0);
    float4 w = *(const float4*)(Wp + k0);
    __syncthreads();
    As[lc + 0][lr] = b2f(a.x); As[lc + 1][lr] = b2f(a.y);
    As[lc + 2][lr] = b2f(a.z); As[lc + 3][lr] = b2f(a.w);
    Ws[lc + 0][lr] = w.x; Ws[lc + 1][lr] = w.y; Ws[lc + 2][lr] = w.z; Ws[lc + 3][lr] = w.w;
    __syncthreads();
#pragma unroll
    for (int kk = 0; kk < 16; ++kk) {
      float4 av = *(const float4*)&As[kk][ty << 2];
      float4 wv = *(const float4*)&Ws[kk][tx << 2];
      float aa[4] = {av.x, av.y, av.z, av.w};
      float ww[4] = {wv.x, wv.y, wv.z, wv.w};
#pragma unroll
      for (int i = 0; i < 4; ++i)
#pragma unroll
        for (int j = 0; j < 4; ++j) acc[i][j] = fmaf(aa[i], ww[j], acc[i][j]);
    }
  }
  float4 bv = *(const float4*)&bias[col0 + (tx << 2)];
  float bb[4] = {bv.x, bv.y, bv.z, bv.w};
#pragma unroll
  for (int i = 0; i < 4; ++i) {
    ushort4 o;
    float v0 = acc[i][0] + bb[0], v1 = acc[i][1] + bb[1];
    float v2 = acc[i][2] + bb[2], v3 = acc[i][3] + bb[3];
    if (ACT == 1) {
      v0 = 0.5f * v0 * (1.0f + erff(v0 * 0.7071067811865476f));
      v1 = 0.5f * v1 * (1.0f + erff(v1 * 0.7071067811865476f));
      v2 = 0.5f * v2 * (1.0f + erff(v2 * 0.7071067811865476f));
      v3 = 0.5f * v3 * (1.0f + erff(v3 * 0.7071067811865476f));
    }
    o.x = f2b(v0); o.y = f2b(v1); o.z = f2b(v2); o.w = f2b(v3);
    *(ushort4*)&C[(size_t)(row0 + (ty << 2) + i) * N + col0 + (tx << 2)] = o;
  }
}

// ---------------- pooled linear attention (in-place on Q) ----------------
// Q: (1024 groups, 64, 256) bf16. CROSS: pooled K from KP (16384,256) bf16;
// else pool Q's own rows. heads H=8, E=32, POOL=16.
template <int CROSS, int CAUSAL>
__global__ __launch_bounds__(512) void lin_attn(u16* __restrict__ Q,
                                                const u16* __restrict__ KP) {
  __shared__ float kpool[16][260];
  int p = blockIdx.x, t = threadIdx.x;
  if (CROSS) {
    for (int idx = t; idx < 4096; idx += 512) {
      int s = idx >> 8, d = idx & 255;
      kpool[s][d] = b2f(KP[((size_t)p * 16 + s) * 256 + d]);
    }
  } else {
    const u16* Kp = Q + (size_t)p * 64 * 256;
    for (int idx = t; idx < 4096; idx += 512) {
      int s = idx >> 8, d = idx & 255;
      const u16* b0 = Kp + (size_t)(4 * s) * 256 + d;
      kpool[s][d] = 0.25f * (b2f(b0[0]) + b2f(b0[256]) + b2f(b0[512]) + b2f(b0[768]));
    }
  }
  __syncthreads();
  int h = t >> 6, l = t & 63;
  u16* q = Q + ((size_t)p * 64 + l) * 256 + h * 32;
  float qr[32];
#pragma unroll
  for (int e = 0; e < 32; e += 4) {
    ushort4 v = *(const ushort4*)&q[e];
    qr[e] = b2f(v.x); qr[e + 1] = b2f(v.y); qr[e + 2] = b2f(v.z); qr[e + 3] = b2f(v.w);
  }
  float sc[16], mx = -INFINITY;
#pragma unroll
  for (int s = 0; s < 16; ++s) {
    const float* kp = &kpool[s][h * 32];
    float d = 0.f;
#pragma unroll
    for (int e = 0; e < 32; ++e) d = fmaf(qr[e], kp[e], d);
    d *= 0.17677669529663687f;  // 1/sqrt(32)
    if (CAUSAL && s > l) d = -INFINITY;
    sc[s] = d; mx = fmaxf(mx, d);
  }
  float sum = 0.f;
#pragma unroll
  for (int s = 0; s < 16; ++s) { sc[s] = expf(sc[s] - mx); sum += sc[s]; }
  float inv = 1.0f / sum;
  float o[32] = {};
#pragma unroll
  for (int s = 0; s < 16; ++s) {
    float a = sc[s] * inv;
    const float* vp = &kpool[s][h * 32];
#pragma unroll
    for (int e = 0; e < 32; ++e) o[e] = fmaf(a, vp[e], o[e]);
  }
#pragma unroll
  for (int e = 0; e < 32; e += 4) {
    ushort4 v;
    v.x = f2b(o[e]); v.y = f2b(o[e + 1]); v.z = f2b(o[e + 2]); v.w = f2b(o[e + 3]);
    *(ushort4*)&q[e] = v;
  }
}

// ---------------- fused GEMM + residual + LayerNorm (in place over R) -----
// R(M,256) <- LN( X(M,K) @ W(256,K)^T + bias + R ).  64 rows/block.
template <int KDIM>
__global__ __launch_bounds__(256) void gemm_resln(const u16* __restrict__ X,
                                                  const float* __restrict__ W,
                                                  const float* __restrict__ bias,
                                                  u16* __restrict__ R,
                                                  const float* __restrict__ lnw,
                                                  const float* __restrict__ lnb) {
  __shared__ float Xs[16][68];
  __shared__ float Ws[16][260];
  int t = threadIdx.x;
  int row0 = blockIdx.x * 64;
  int tx = t & 15, ty = t >> 4;
  int r0 = ty << 2;
  float acc[4][16] = {};
  const u16* Xp = X + (size_t)(row0 + (t >> 2)) * KDIM + ((t & 3) << 2);
  const float* Wp = W + (size_t)t * KDIM;
  for (int k0 = 0; k0 < KDIM; k0 += 16) {
    ushort4 xa = *(const ushort4*)(Xp + k0);
    float4 w0 = *(const float4*)(Wp + k0);
    float4 w1 = *(const float4*)(Wp + k0 + 4);
    float4 w2 = *(const float4*)(Wp + k0 + 8);
    float4 w3 = *(const float4*)(Wp + k0 + 12);
    __syncthreads();
    int lr = t >> 2, lc = (t & 3) << 2;
    Xs[lc + 0][lr] = b2f(xa.x); Xs[lc + 1][lr] = b2f(xa.y);
    Xs[lc + 2][lr] = b2f(xa.z); Xs[lc + 3][lr] = b2f(xa.w);
    Ws[0][t] = w0.x; Ws[1][t] = w0.y; Ws[2][t] = w0.z; Ws[3][t] = w0.w;
    Ws[4][t] = w1.x; Ws[5][t] = w1.y; Ws[6][t] = w1.z; Ws[7][t] = w1.w;
    Ws[8][t] = w2.x; Ws[9][t] = w2.y; Ws[10][t] = w2.z; Ws[11][t] = w2.w;
    Ws[12][t] = w3.x; Ws[13][t] = w3.y; Ws[14][t] = w3.z; Ws[15][t] = w3.w;
    __syncthreads();
#pragma unroll
    for (int kk = 0; kk < 16; ++kk) {
      float a0 = Xs[kk][r0], a1 = Xs[kk][r0 + 1], a2 = Xs[kk][r0 + 2], a3 = Xs[kk][r0 + 3];
#pragma unroll
      for (int u = 0; u < 4; ++u) {
        float4 wv = *(const float4*)&Ws[kk][u * 64 + (tx << 2)];
        float ww[4] = {wv.x, wv.y, wv.z, wv.w};
#pragma unroll
        for (int j = 0; j < 4; ++j) {
          acc[0][u * 4 + j] = fmaf(a0, ww[j], acc[0][u * 4 + j]);
          acc[1][u * 4 + j] = fmaf(a1, ww[j], acc[1][u * 4 + j]);
          acc[2][u * 4 + j] = fmaf(a2, ww[j], acc[2][u * 4 + j]);
          acc[3][u * 4 + j] = fmaf(a3, ww[j], acc[3][u * 4 + j]);
        }
      }
    }
  }
  float bb[16];
#pragma unroll
  for (int u = 0; u < 4; ++u) {
    float4 bv = *(const float4*)&bias[u * 64 + (tx << 2)];
    bb[u * 4] = bv.x; bb[u * 4 + 1] = bv.y; bb[u * 4 + 2] = bv.z; bb[u * 4 + 3] = bv.w;
  }
#pragma unroll
  for (int i = 0; i < 4; ++i) {
    size_t roff = (size_t)(row0 + r0 + i) * 256;
#pragma unroll
    for (int u = 0; u < 4; ++u) {
      ushort4 rv = *(const ushort4*)&R[roff + u * 64 + (tx << 2)];
      acc[i][u * 4 + 0] += bb[u * 4 + 0] + b2f(rv.x);
      acc[i][u * 4 + 1] += bb[u * 4 + 1] + b2f(rv.y);
      acc[i][u * 4 + 2] += bb[u * 4 + 2] + b2f(rv.z);
      acc[i][u * 4 + 3] += bb[u * 4 + 3] + b2f(rv.w);
    }
    float s = 0.f, s2 = 0.f;
#pragma unroll
    for (int c = 0; c < 16; ++c) { float x = acc[i][c]; s += x; s2 = fmaf(x, x, s2); }
#pragma unroll
    for (int o = 1; o < 16; o <<= 1) { s += __shfl_xor(s, o); s2 += __shfl_xor(s2, o); }
    float mu = s * (1.0f / 256.0f);
    float var = fmaxf(s2 * (1.0f / 256.0f) - mu * mu, 0.0f);
    float rs = rsqrtf(var + 1e-5f);
#pragma unroll
    for (int u = 0; u < 4; ++u) {
      float4 lw = *(const float4*)&lnw[u * 64 + (tx << 2)];
      float4 lb = *(const float4*)&lnb[u * 64 + (tx << 2)];
      ushort4 ov;
      ov.x = f2b((acc[i][u * 4 + 0] - mu) * rs * lw.x + lb.x);
      ov.y = f2b((acc[i][u * 4 + 1] - mu) * rs * lw.y + lb.y);
      ov.z = f2b((acc[i][u * 4 + 2] - mu) * rs * lw.z + lb.z);
      ov.w = f2b((acc[i][u * 4 + 3] - mu) * rs * lw.w + lb.w);
      *(ushort4*)&R[roff + u * 64 + (tx << 2)] = ov;
    }
  }
}

// ---------------- plain LayerNorm (in place), bf16 ------------------------
__global__ __launch_bounds__(256) void ln_bf(u16* __restrict__ X,
                                             const float* __restrict__ w,
                                             const float* __restrict__ b) {
  int lane = threadIdx.x & 63, wv = threadIdx.x >> 6;
  size_t row = (size_t)blockIdx.x * 4 + wv;
  size_t off = row * 256 + lane * 4;
  ushort4 xv = *(const ushort4*)(X + off);
  float v0 = b2f(xv.x), v1 = b2f(xv.y), v2 = b2f(xv.z), v3 = b2f(xv.w);
  float s = v0 + v1 + v2 + v3;
  float s2 = v0 * v0 + v1 * v1 + v2 * v2 + v3 * v3;
#pragma unroll
  for (int o = 32; o; o >>= 1) { s += __shfl_xor(s, o); s2 += __shfl_xor(s2, o); }
  float mu = s * (1.0f / 256.0f);
  float var = fmaxf(s2 * (1.0f / 256.0f) - mu * mu, 0.0f);
  float rs = rsqrtf(var + 1e-5f);
  float4 w4 = *(const float4*)(w + lane * 4);
  float4 b4 = *(const float4*)(b + lane * 4);
  ushort4 o4;
  o4.x = f2b((v0 - mu) * rs * w4.x + b4.x);
  o4.y = f2b((v1 - mu) * rs * w4.y + b4.y);
  o4.z = f2b((v2 - mu) * rs * w4.z + b4.z);
  o4.w = f2b((v3 - mu) * rs * w4.w + b4.w);
  *(ushort4*)(X + off) = o4;
}

// ---------------- pool over j (4:1), bf16 -> bf16 -------------------------
__global__ void pool_bf(const u16* __restrict__ A, u16* __restrict__ P) {
  int r = blockIdx.x, d = threadIdx.x;  // r < 16384
  int g = r >> 4, s = r & 15;
  const u16* src = A + ((size_t)g * 64 + 4 * (size_t)s) * 256 + d;
  float v = 0.25f * (b2f(src[0]) + b2f(src[256]) + b2f(src[512]) + b2f(src[768]));
  P[(size_t)r * 256 + d] = f2b(v);
}

// ---------------- Weff = Wo[:, :256] + Wo[:, 256:] ------------------------
__global__ void weff_kernel(const float* __restrict__ Wo, float* __restrict__ Weff) {
  int n = blockIdx.x, k = threadIdx.x;
  Weff[n * 256 + k] = Wo[n * 512 + k] + Wo[n * 512 + 256 + k];
}

// ---------------- mean over j + final projection + slice ------------------
__global__ __launch_bounds__(256) void mean_proj_bf(const u16* __restrict__ X,
                                                    const float* __restrict__ pw,
                                                    const float* __restrict__ pb,
                                                    float* __restrict__ out) {
  int bid = blockIdx.x;  // 0..511
  int b = bid >> 5, ii = bid & 31;
  int i = 32 + ii;
  __shared__ float md[256];
  int d = threadIdx.x;
  const u16* base = X + ((size_t)b * 64 + i) * 64 * 256 + d;
  float s = 0.f;
  for (int j = 0; j < 64; ++j) s += b2f(base[(size_t)j * 256]);
  md[d] = s * (1.0f / 64.0f);
  __syncthreads();
  if (d < 64) {
    float acc = pb[d];
    const float* wr = pw + d * 256;
    for (int k = 0; k < 256; ++k) acc = fmaf(md[k], wr[k], acc);
    out[((size_t)b * 32 + ii) * 64 + d] = acc;
  }
}

// ---------------------------------------------------------------------------
extern "C" void kernel_launch(void* const* d_in, const int* in_sizes, int n_in,
                              void* d_out, int out_size, void* d_ws, size_t ws_size,
                              hipStream_t stream) {
  (void)in_sizes; (void)out_size;
  if (n_in < 50) return;

  const float* x_enc = (const float*)d_in[0];
  const float* x_dec = (const float*)d_in[1];
  const float* enc_sproj_w = (const float*)d_in[2];
  const float* enc_sproj_b = (const float*)d_in[3];
  const float* enc_scproj_w = (const float*)d_in[4];
  const float* enc_scproj_b = (const float*)d_in[5];
  const float* enc_tok_w = (const float*)d_in[6];
  const float* enc_tok_b = (const float*)d_in[7];
  const float* dec_sproj_w = (const float*)d_in[8];
  const float* dec_sproj_b = (const float*)d_in[9];
  const float* dec_scproj_w = (const float*)d_in[10];
  const float* dec_scproj_b = (const float*)d_in[11];
  const float* dec_tok_w = (const float*)d_in[12];
  const float* dec_tok_b = (const float*)d_in[13];
  const float* e_Wq = (const float*)d_in[14];
  const float* e_bq = (const float*)d_in[15];
  const float* e_Wo = (const float*)d_in[16];
  const float* e_bo = (const float*)d_in[17];
  const float* e_c1w = (const float*)d_in[18];
  const float* e_c1b = (const float*)d_in[19];
  const float* e_c2w = (const float*)d_in[20];
  const float* e_c2b = (const float*)d_in[21];
  const float* e_ln1w = (const float*)d_in[22];
  const float* e_ln1b = (const float*)d_in[23];
  const float* e_ln2w = (const float*)d_in[24];
  const float* e_ln2b = (const float*)d_in[25];
  const float* enc_norm_w = (const float*)d_in[26];
  const float* enc_norm_b = (const float*)d_in[27];
  const float* d_sWq = (const float*)d_in[28];
  const float* d_sbq = (const float*)d_in[29];
  const float* d_sWo = (const float*)d_in[30];
  const float* d_sbo = (const float*)d_in[31];
  const float* d_cWq = (const float*)d_in[32];
  const float* d_cbq = (const float*)d_in[33];
  const float* d_cWo = (const float*)d_in[34];
  const float* d_cbo = (const float*)d_in[35];
  const float* d_c1w = (const float*)d_in[36];
  const float* d_c1b = (const float*)d_in[37];
  const float* d_c2w = (const float*)d_in[38];
  const float* d_c2b = (const float*)d_in[39];
  const float* d_ln1w = (const float*)d_in[40];
  const float* d_ln1b = (const float*)d_in[41];
  const float* d_ln2w = (const float*)d_in[42];
  const float* d_ln2b = (const float*)d_in[43];
  const float* d_ln3w = (const float*)d_in[44];
  const float* d_ln3b = (const float*)d_in[45];
  const float* dec_norm_w = (const float*)d_in[46];
  const float* dec_norm_b = (const float*)d_in[47];
  const float* proj_w = (const float*)d_in[48];
  const float* proj_b = (const float*)d_in[49];

  // ---- workspace layout ----
  const size_t ACT = 16777216;           // 65536*256 elements
  const size_t POOLE = 4194304;          // 16384*256 elements
  size_t fixed_bytes = 3 * ACT * 2       // A_enc, A_dec, T1 (bf16)
                     + 2 * POOLE * 2     // PA, PK (bf16)
                     + (size_t)(16384 + 65536 + 147456 + 98304 + 65536) * 4;  // f32 misc
  int hf_rows = 0;
  for (int r = 16384; r >= 2048; r >>= 1)
    if (fixed_bytes + (size_t)r * 1024 * 2 <= ws_size) { hf_rows = r; break; }
  if (!hf_rows) {
    // workspace too small even for minimum plan: reveal ws_size via absmax.
    ws_signal<<<1, 1, 0, stream>>>((float*)d_out, (float)(ws_size >> 20));
    return;
  }

  char* wsb = (char*)d_ws;
  u16* A_enc = (u16*)wsb;                 wsb += ACT * 2;
  u16* A_dec = (u16*)wsb;                 wsb += ACT * 2;
  u16* T1 = (u16*)wsb;                    wsb += ACT * 2;
  u16* PA = (u16*)wsb;                    wsb += POOLE * 2;
  u16* PK = (u16*)wsb;                    wsb += POOLE * 2;
  u16* HF = (u16*)wsb;                    wsb += (size_t)hf_rows * 1024 * 2;
  float* PE = (float*)wsb;                wsb += 16384 * 4;
  float* WEFF = (float*)wsb;              wsb += 65536 * 4;
  float* EH1 = (float*)wsb;               wsb += 147456 * 4;
  float* EH2 = (float*)wsb;               wsb += 98304 * 4;
  float* EH3 = (float*)wsb;               wsb += 65536 * 4;

  pe_kernel<<<64, 256, 0, stream>>>(PE);

  // ---- encoder embedding ----
  conv_sproj<<<dim3(96, 16), 96, 0, stream>>>(x_enc, enc_sproj_w, enc_sproj_b, EH1);
  conv_scproj_t<<<dim3(64, 16), 96, 0, stream>>>(EH1, enc_scproj_w, enc_scproj_b, EH2);
  conv_scproj_s<<<dim3(64, 16), 64, 0, stream>>>(EH2, enc_scproj_w, enc_scproj_b, EH3);
  tok_embed<<<1024, 256, 0, stream>>>(EH3, enc_tok_w, enc_tok_b, PE, A_enc);

  // ---- encoder layers ----
  for (int i = 0; i < 3; ++i) {
    gemm_bf16<0><<<dim3(4, 1024), 256, 0, stream>>>(A_enc, e_Wq + (size_t)i * 65536,
                                                    e_bq + i * 256, T1, 256, 256);
    lin_attn<0, 0><<<1024, 512, 0, stream>>>(T1, nullptr);
    weff_kernel<<<256, 256, 0, stream>>>(e_Wo + (size_t)i * 131072, WEFF);
    gemm_resln<256><<<1024, 256, 0, stream>>>(T1, WEFF, e_bo + i * 256, A_enc,
                                              e_ln1w + i * 256, e_ln1b + i * 256);
    for (int m0 = 0; m0 < 65536; m0 += hf_rows) {
      gemm_bf16<1><<<dim3(16, hf_rows / 64), 256, 0, stream>>>(
          A_enc + (size_t)m0 * 256, e_c1w + (size_t)i * 262144, e_c1b + i * 1024,
          HF, 1024, 256);
      gemm_resln<1024><<<hf_rows / 64, 256, 0, stream>>>(
          HF, e_c2w + (size_t)i * 262144, e_c2b + i * 256, A_enc + (size_t)m0 * 256,
          e_ln2w + i * 256, e_ln2b + i * 256);
    }
  }
  ln_bf<<<16384, 256, 0, stream>>>(A_enc, enc_norm_w, enc_norm_b);
  pool_bf<<<16384, 256, 0, stream>>>(A_enc, PA);

  // ---- decoder embedding ----
  conv_sproj<<<dim3(96, 16), 96, 0, stream>>>(x_dec, dec_sproj_w, dec_sproj_b, EH1);
  conv_scproj_t<<<dim3(64, 16), 96, 0, stream>>>(EH1, dec_scproj_w, dec_scproj_b, EH2);
  conv_scproj_s<<<dim3(64, 16), 64, 0, stream>>>(EH2, dec_scproj_w, dec_scproj_b, EH3);
  tok_embed<<<1024, 256, 0, stream>>>(EH3, dec_tok_w, dec_tok_b, PE, A_dec);

  // ---- decoder layers ----
  for (int i = 0; i < 2; ++i) {
    // self-attention (causal)
    gemm_bf16<0><<<dim3(4, 1024), 256, 0, stream>>>(A_dec, d_sWq + (size_t)i * 65536,
                                                    d_sbq + i * 256, T1, 256, 256);
    lin_attn<0, 1><<<1024, 512, 0, stream>>>(T1, nullptr);
    weff_kernel<<<256, 256, 0, stream>>>(d_sWo + (size_t)i * 131072, WEFF);
    gemm_resln<256><<<1024, 256, 0, stream>>>(T1, WEFF, d_sbo + i * 256, A_dec,
                                              d_ln1w + i * 256, d_ln1b + i * 256);
    // cross-attention: q = h @ cWq ; pooled k = pool(enc) @ cWq
    gemm_bf16<0><<<dim3(4, 1024), 256, 0, stream>>>(A_dec, d_cWq + (size_t)i * 65536,
                                                    d_cbq + i * 256, T1, 256, 256);
    gemm_bf16<0><<<dim3(4, 256), 256, 0, stream>>>(PA, d_cWq + (size_t)i * 65536,
                                                   d_cbq + i * 256, PK, 256, 256);
    lin_attn<1, 0><<<1024, 512, 0, stream>>>(T1, PK);
    weff_kernel<<<256, 256, 0, stream>>>(d_cWo + (size_t)i * 131072, WEFF);
    gemm_resln<256><<<1024, 256, 0, stream>>>(T1, WEFF, d_cbo + i * 256, A_dec,
                                              d_ln2w + i * 256, d_ln2b + i * 256);
    // FFN
    for (int m0 = 0; m0 < 65536; m0 += hf_rows) {
      gemm_bf16<1><<<dim3(16, hf_rows / 64), 256, 0, stream>>>(
          A_dec + (size_t)m0 * 256, d_c1w + (size_t)i * 262144, d_c1b + i * 1024,
          HF, 1024, 256);
      gemm_resln<1024><<<hf_rows / 64, 256, 0, stream>>>(
          HF, d_c2w + (size_t)i * 262144, d_c2b + i * 256, A_dec + (size_t)m0 * 256,
          d_ln3w + i * 256, d_ln3b + i * 256);
    }
  }
  ln_bf<<<16384, 256, 0, stream>>>(A_dec, dec_norm_w, dec_norm_b);

  mean_proj_bf<<<512, 256, 0, stream>>>(A_dec, proj_w, proj_b, (float*)d_out);
}

// Round 3
// 2312.931 us; speedup vs baseline: 3.1203x; 3.1203x over previous
//
#include <hip/hip_runtime.h>

// ---------------------------------------------------------------------------
// STLT forward. bf16 activations+weights, MFMA GEMMs (16x16x32 bf16), f32
// accum/epilogues. Activations flat (65536, 256) rows = (b, i, j).
// T==S==64 => qt==qs, kt==ks: Weff = Wo[:, :256] + Wo[:, 256:].
// ---------------------------------------------------------------------------

typedef unsigned short u16;
typedef short s16;
typedef __attribute__((ext_vector_type(8))) s16 bfrag;   // 8 bf16 = 4 VGPR
typedef __attribute__((ext_vector_type(4))) float f32x4; // MFMA C/D

__device__ __forceinline__ float b2f(u16 u) {
  union { float f; unsigned int i; } v; v.i = ((unsigned int)u) << 16; return v.f;
}
__device__ __forceinline__ u16 f2b(float f) {
  union { float f; unsigned int i; } v; v.f = f;
  unsigned int x = v.i;
  return (u16)((x + 0x7FFFu + ((x >> 16) & 1u)) >> 16);
}

__global__ void ws_signal(float* out, float v) { out[0] = v; }

// ---------------- weight conversion ----------------------------------------
__global__ void cvt_bf(const float* __restrict__ src, u16* __restrict__ dst, int n) {
  int i = blockIdx.x * 256 + threadIdx.x;
  if (i < n) dst[i] = f2b(src[i]);
}
// Weff (256x256 bf16) = Wo[:, :256] + Wo[:, 256:]
__global__ void weff_bf(const float* __restrict__ Wo, u16* __restrict__ W) {
  int n = blockIdx.x, k = threadIdx.x;
  W[n * 256 + k] = f2b(Wo[n * 512 + k] + Wo[n * 512 + 256 + k]);
}

// ---------------- positional encoding --------------------------------------
__global__ void pe_kernel(float* __restrict__ pe) {
  int l = blockIdx.x, d = threadIdx.x;
  int i = d >> 1;
  float div = expf((float)(2 * i) * (-9.210340371976184f / 256.0f));
  float ang = (float)l * div;
  pe[l * 256 + d] = (d & 1) ? cosf(ang) : sinf(ang);
}

// ---------------- embedding convs (circular, K=3), f32 ---------------------
__global__ void conv_sproj(const float* __restrict__ x, const float* __restrict__ w,
                           const float* __restrict__ bias, float* __restrict__ h1) {
  int o = blockIdx.x, b = blockIdx.y, l = threadIdx.x;  // l < 96
  const float* wo = w + o * 192;
  const float* xb = x + (size_t)b * 96 * 64;
  float acc = bias[o];
#pragma unroll
  for (int k = 0; k < 3; ++k) {
    int lp = l + k - 1; if (lp < 0) lp += 96; if (lp >= 96) lp -= 96;
    const float* xr = xb + lp * 64;
    for (int c = 0; c < 64; ++c) acc = fmaf(xr[c], wo[c * 3 + k], acc);
  }
  h1[((size_t)b * 96 + o) * 96 + l] = acc;
}

__global__ void conv_scproj_t(const float* __restrict__ h1, const float* __restrict__ w,
                              const float* __restrict__ bias, float* __restrict__ h2) {
  int o = blockIdx.x, b = blockIdx.y, l = threadIdx.x;  // o<64, l<96
  const float* wo = w + o * 288;
  const float* hb = h1 + (size_t)b * 96 * 96;
  float acc = bias[o];
#pragma unroll
  for (int k = 0; k < 3; ++k) {
    int lp = l + k - 1; if (lp < 0) lp += 96; if (lp >= 96) lp -= 96;
    for (int c = 0; c < 96; ++c) acc = fmaf(hb[c * 96 + lp], wo[c * 3 + k], acc);
  }
  h2[((size_t)b * 64 + o) * 96 + l] = acc;
}

__global__ void conv_scproj_s(const float* __restrict__ h2, const float* __restrict__ w,
                              const float* __restrict__ bias, float* __restrict__ h3) {
  int o = blockIdx.x, b = blockIdx.y, l = threadIdx.x;  // o<64, l<64
  const float* wo = w + o * 288;
  const float* hb = h2 + (size_t)b * 64 * 96;
  float acc = bias[o];
#pragma unroll
  for (int k = 0; k < 3; ++k) {
    int lp = l + k - 1; if (lp < 0) lp += 64; if (lp >= 64) lp -= 64;
    for (int c = 0; c < 96; ++c) acc = fmaf(hb[lp * 96 + c], wo[c * 3 + k], acc);
  }
  h3[((size_t)b * 64 + o) * 64 + l] = acc;
}

__global__ void tok_embed(const float* __restrict__ h3, const float* __restrict__ w,
                          const float* __restrict__ bias, const float* __restrict__ pe,
                          u16* __restrict__ E) {
  int g = blockIdx.x, d = threadIdx.x;
  __shared__ float row[64];
  if (d < 64) row[d] = h3[(size_t)g * 64 + d];
  __syncthreads();
  float w0 = w[d * 3], w1 = w[d * 3 + 1], w2 = w[d * 3 + 2], bd = bias[d];
  for (int j = 0; j < 64; ++j) {
    int jm = (j + 63) & 63, jp = (j + 1) & 63;
    float v = bd + row[jm] * w0 + row[j] * w1 + row[jp] * w2 + pe[j * 256 + d];
    E[((size_t)g * 64 + j) * 256 + d] = f2b(v);
  }
}

// ---------------- MFMA GEMM: C(M,N) = A(M,K) @ W(N,K)^T + bias -------------
// 128x128 tile, 256 thr (4 waves 2x2, each 64x64 = 4x4 frags 16x16).
// LDS subtiled layout: frag f of 16-row group stored as 64 lanes x 16B runs
// => ds_read_b128 sequential (conflict-free). ACT: 0=none, 1=exact GELU.
template <int ACT>
__global__ __launch_bounds__(256) void mfma_gemm(const u16* __restrict__ A,
                                                 const u16* __restrict__ W,
                                                 const float* __restrict__ bias,
                                                 u16* __restrict__ C, int N, int K) {
  __shared__ s16 As[4096];  // 8 msub x 64 lane x 8 bf16  (128 rows x 32 k)
  __shared__ s16 Bs[4096];
  int t = threadIdx.x;
  int wave = t >> 6, lane = t & 63;
  int wr = wave >> 1, wc = wave & 1;
  int row0 = blockIdx.y * 128, col0 = blockIdx.x * 128;
  f32x4 acc[4][4];
#pragma unroll
  for (int m = 0; m < 4; ++m)
#pragma unroll
    for (int n = 0; n < 4; ++n) acc[m][n] = (f32x4){0.f, 0.f, 0.f, 0.f};
  for (int k0 = 0; k0 < K; k0 += 32) {
#pragma unroll
    for (int i = 0; i < 2; ++i) {
      int idx = t + i * 256;              // 512 loads: 128 rows x 4 kchunks
      int r = idx >> 2, kc = idx & 3;
      uint4 va = *(const uint4*)(A + (size_t)(row0 + r) * K + k0 + kc * 8);
      uint4 vb = *(const uint4*)(W + (size_t)(col0 + r) * K + k0 + kc * 8);
      int d = ((r >> 4) * 64 + (r & 15) + kc * 16) * 8;
      __syncthreads();
      *(uint4*)(As + d) = va;
      *(uint4*)(Bs + d) = vb;
    }
    __syncthreads();
    bfrag af[4], bf[4];
#pragma unroll
    for (int m = 0; m < 4; ++m) af[m] = *(const bfrag*)(As + ((wr * 4 + m) * 64 + lane) * 8);
#pragma unroll
    for (int n = 0; n < 4; ++n) bf[n] = *(const bfrag*)(Bs + ((wc * 4 + n) * 64 + lane) * 8);
#pragma unroll
    for (int m = 0; m < 4; ++m)
#pragma unroll
      for (int n = 0; n < 4; ++n)
        acc[m][n] = __builtin_amdgcn_mfma_f32_16x16x32_bf16(af[m], bf[n], acc[m][n], 0, 0, 0);
    __syncthreads();
  }
  int rbase = row0 + wr * 64 + ((lane >> 4) << 2);
  int cbase = col0 + wc * 64 + (lane & 15);
#pragma unroll
  for (int n = 0; n < 4; ++n) {
    int col = cbase + n * 16;
    float bcol = bias[col];
#pragma unroll
    for (int m = 0; m < 4; ++m) {
#pragma unroll
      for (int r = 0; r < 4; ++r) {
        float v = acc[m][n][r] + bcol;
        if (ACT == 1) v = 0.5f * v * (1.0f + erff(v * 0.7071067811865476f));
        C[(size_t)(rbase + m * 16 + r) * N + col] = f2b(v);
      }
    }
  }
}

// ---------------- MFMA GEMM + bias + residual + LayerNorm (N=256) ----------
// R(M,256) <- LN( X(M,K) @ W(256,K)^T + bias + R ). 128 rows/block, 512 thr
// (8 waves 2x4). Block owns full rows => LN in epilogue via LDS partials.
__global__ __launch_bounds__(512) void mfma_gemm_resln(const u16* __restrict__ X,
                                                       const u16* __restrict__ W,
                                                       const float* __restrict__ bias,
                                                       u16* __restrict__ R,
                                                       const float* __restrict__ lnw,
                                                       const float* __restrict__ lnb,
                                                       int K) {
  __shared__ s16 As[4096];   // 128 rows x 32 k
  __shared__ s16 Bs[8192];   // 256 rows x 32 k
  __shared__ float pls[128][4][2];
  int t = threadIdx.x;
  int wave = t >> 6, lane = t & 63;
  int wr = wave >> 2, wc = wave & 3;
  int row0 = blockIdx.x * 128;
  f32x4 acc[4][4];
#pragma unroll
  for (int m = 0; m < 4; ++m)
#pragma unroll
    for (int n = 0; n < 4; ++n) acc[m][n] = (f32x4){0.f, 0.f, 0.f, 0.f};
  for (int k0 = 0; k0 < K; k0 += 32) {
    {
      int r = t >> 2, kc = t & 3;       // 512 A loads: 1/thread
      uint4 va = *(const uint4*)(X + (size_t)(row0 + r) * K + k0 + kc * 8);
      uint4 vb0, vb1;
      {
        int idx = t, r2 = idx >> 2, kc2 = idx & 3;
        vb0 = *(const uint4*)(W + (size_t)r2 * K + k0 + kc2 * 8);
        idx = t + 512; r2 = idx >> 2; kc2 = idx & 3;
        vb1 = *(const uint4*)(W + (size_t)r2 * K + k0 + kc2 * 8);
      }
      __syncthreads();
      *(uint4*)(As + ((r >> 4) * 64 + (r & 15) + kc * 16) * 8) = va;
      {
        int idx = t, r2 = idx >> 2, kc2 = idx & 3;
        *(uint4*)(Bs + ((r2 >> 4) * 64 + (r2 & 15) + kc2 * 16) * 8) = vb0;
        idx = t + 512; r2 = idx >> 2; kc2 = idx & 3;
        *(uint4*)(Bs + ((r2 >> 4) * 64 + (r2 & 15) + kc2 * 16) * 8) = vb1;
      }
    }
    __syncthreads();
    bfrag af[4], bf[4];
#pragma unroll
    for (int m = 0; m < 4; ++m) af[m] = *(const bfrag*)(As + ((wr * 4 + m) * 64 + lane) * 8);
#pragma unroll
    for (int n = 0; n < 4; ++n) bf[n] = *(const bfrag*)(Bs + ((wc * 4 + n) * 64 + lane) * 8);
#pragma unroll
    for (int m = 0; m < 4; ++m)
#pragma unroll
      for (int n = 0; n < 4; ++n)
        acc[m][n] = __builtin_amdgcn_mfma_f32_16x16x32_bf16(af[m], bf[n], acc[m][n], 0, 0, 0);
    __syncthreads();
  }
  // epilogue: bias + residual, then row LN across the 4 wc-waves
  int g4 = (lane >> 4) << 2;            // row sub-offset
  int cl = lane & 15;
  float lw[4], lb[4], bc[4];
#pragma unroll
  for (int n = 0; n < 4; ++n) {
    int col = wc * 64 + n * 16 + cl;
    bc[n] = bias[col]; lw[n] = lnw[col]; lb[n] = lnb[col];
  }
#pragma unroll
  for (int m = 0; m < 4; ++m) {
#pragma unroll
    for (int r = 0; r < 4; ++r) {
      int row = row0 + wr * 64 + m * 16 + g4 + r;
      float s = 0.f, s2 = 0.f;
#pragma unroll
      for (int n = 0; n < 4; ++n) {
        int col = wc * 64 + n * 16 + cl;
        float v = acc[m][n][r] + bc[n] + b2f(R[(size_t)row * 256 + col]);
        acc[m][n][r] = v;
        s += v; s2 = fmaf(v, v, s2);
      }
#pragma unroll
      for (int o = 1; o < 16; o <<= 1) { s += __shfl_xor(s, o); s2 += __shfl_xor(s2, o); }
      if (cl == 0) {
        int rl = wr * 64 + m * 16 + g4 + r;
        pls[rl][wc][0] = s; pls[rl][wc][1] = s2;
      }
    }
  }
  __syncthreads();
#pragma unroll
  for (int m = 0; m < 4; ++m) {
#pragma unroll
    for (int r = 0; r < 4; ++r) {
      int rl = wr * 64 + m * 16 + g4 + r;
      float s = pls[rl][0][0] + pls[rl][1][0] + pls[rl][2][0] + pls[rl][3][0];
      float s2 = pls[rl][0][1] + pls[rl][1][1] + pls[rl][2][1] + pls[rl][3][1];
      float mu = s * (1.0f / 256.0f);
      float var = fmaxf(s2 * (1.0f / 256.0f) - mu * mu, 0.0f);
      float rs = rsqrtf(var + 1e-5f);
      int row = row0 + wr * 64 + m * 16 + g4 + r;
#pragma unroll
      for (int n = 0; n < 4; ++n) {
        int col = wc * 64 + n * 16 + cl;
        R[(size_t)row * 256 + col] = f2b((acc[m][n][r] - mu) * rs * lw[n] + lb[n]);
      }
    }
  }
}

// ---------------- pooled linear attention (in-place on Q) ------------------
template <int CROSS, int CAUSAL>
__global__ __launch_bounds__(512) void lin_attn(u16* __restrict__ Q,
                                                const u16* __restrict__ KP) {
  __shared__ float kpool[16][260];
  int p = blockIdx.x, t = threadIdx.x;
  if (CROSS) {
    for (int idx = t; idx < 4096; idx += 512) {
      int s = idx >> 8, d = idx & 255;
      kpool[s][d] = b2f(KP[((size_t)p * 16 + s) * 256 + d]);
    }
  } else {
    const u16* Kp = Q + (size_t)p * 64 * 256;
    for (int idx = t; idx < 4096; idx += 512) {
      int s = idx >> 8, d = idx & 255;
      const u16* b0 = Kp + (size_t)(4 * s) * 256 + d;
      kpool[s][d] = 0.25f * (b2f(b0[0]) + b2f(b0[256]) + b2f(b0[512]) + b2f(b0[768]));
    }
  }
  __syncthreads();
  int h = t >> 6, l = t & 63;
  u16* q = Q + ((size_t)p * 64 + l) * 256 + h * 32;
  float qr[32];
#pragma unroll
  for (int e = 0; e < 32; e += 4) {
    ushort4 v = *(const ushort4*)&q[e];
    qr[e] = b2f(v.x); qr[e + 1] = b2f(v.y); qr[e + 2] = b2f(v.z); qr[e + 3] = b2f(v.w);
  }
  float sc[16], mx = -INFINITY;
#pragma unroll
  for (int s = 0; s < 16; ++s) {
    const float* kp = &kpool[s][h * 32];
    float d = 0.f;
#pragma unroll
    for (int e = 0; e < 32; ++e) d = fmaf(qr[e], kp[e], d);
    d *= 0.17677669529663687f;
    if (CAUSAL && s > l) d = -INFINITY;
    sc[s] = d; mx = fmaxf(mx, d);
  }
  float sum = 0.f;
#pragma unroll
  for (int s = 0; s < 16; ++s) { sc[s] = expf(sc[s] - mx); sum += sc[s]; }
  float inv = 1.0f / sum;
  float o[32] = {};
#pragma unroll
  for (int s = 0; s < 16; ++s) {
    float a = sc[s] * inv;
    const float* vp = &kpool[s][h * 32];
#pragma unroll
    for (int e = 0; e < 32; ++e) o[e] = fmaf(a, vp[e], o[e]);
  }
#pragma unroll
  for (int e = 0; e < 32; e += 4) {
    ushort4 v;
    v.x = f2b(o[e]); v.y = f2b(o[e + 1]); v.z = f2b(o[e + 2]); v.w = f2b(o[e + 3]);
    *(ushort4*)&q[e] = v;
  }
}

// ---------------- plain LayerNorm (in place), bf16 -------------------------
__global__ __launch_bounds__(256) void ln_bf(u16* __restrict__ X,
                                             const float* __restrict__ w,
                                             const float* __restrict__ b) {
  int lane = threadIdx.x & 63, wv = threadIdx.x >> 6;
  size_t row = (size_t)blockIdx.x * 4 + wv;
  size_t off = row * 256 + lane * 4;
  ushort4 xv = *(const ushort4*)(X + off);
  float v0 = b2f(xv.x), v1 = b2f(xv.y), v2 = b2f(xv.z), v3 = b2f(xv.w);
  float s = v0 + v1 + v2 + v3;
  float s2 = v0 * v0 + v1 * v1 + v2 * v2 + v3 * v3;
#pragma unroll
  for (int o = 32; o; o >>= 1) { s += __shfl_xor(s, o); s2 += __shfl_xor(s2, o); }
  float mu = s * (1.0f / 256.0f);
  float var = fmaxf(s2 * (1.0f / 256.0f) - mu * mu, 0.0f);
  float rs = rsqrtf(var + 1e-5f);
  float4 w4 = *(const float4*)(w + lane * 4);
  float4 b4 = *(const float4*)(b + lane * 4);
  ushort4 o4;
  o4.x = f2b((v0 - mu) * rs * w4.x + b4.x);
  o4.y = f2b((v1 - mu) * rs * w4.y + b4.y);
  o4.z = f2b((v2 - mu) * rs * w4.z + b4.z);
  o4.w = f2b((v3 - mu) * rs * w4.w + b4.w);
  *(ushort4*)(X + off) = o4;
}

// ---------------- pool over j (4:1) ----------------------------------------
__global__ void pool_bf(const u16* __restrict__ A, u16* __restrict__ P) {
  int r = blockIdx.x, d = threadIdx.x;
  int g = r >> 4, s = r & 15;
  const u16* src = A + ((size_t)g * 64 + 4 * (size_t)s) * 256 + d;
  float v = 0.25f * (b2f(src[0]) + b2f(src[256]) + b2f(src[512]) + b2f(src[768]));
  P[(size_t)r * 256 + d] = f2b(v);
}

// ---------------- mean over j + final projection + slice -------------------
__global__ __launch_bounds__(256) void mean_proj_bf(const u16* __restrict__ X,
                                                    const float* __restrict__ pw,
                                                    const float* __restrict__ pb,
                                                    float* __restrict__ out) {
  int bid = blockIdx.x;
  int b = bid >> 5, ii = bid & 31;
  int i = 32 + ii;
  __shared__ float md[256];
  int d = threadIdx.x;
  const u16* base = X + ((size_t)b * 64 + i) * 64 * 256 + d;
  float s = 0.f;
  for (int j = 0; j < 64; ++j) s += b2f(base[(size_t)j * 256]);
  md[d] = s * (1.0f / 64.0f);
  __syncthreads();
  if (d < 64) {
    float acc = pb[d];
    const float* wr = pw + d * 256;
    for (int k = 0; k < 256; ++k) acc = fmaf(md[k], wr[k], acc);
    out[((size_t)b * 32 + ii) * 64 + d] = acc;
  }
}

// ---------------------------------------------------------------------------
extern "C" void kernel_launch(void* const* d_in, const int* in_sizes, int n_in,
                              void* d_out, int out_size, void* d_ws, size_t ws_size,
                              hipStream_t stream) {
  (void)in_sizes; (void)out_size;
  if (n_in < 50) return;

  const float* x_enc = (const float*)d_in[0];
  const float* x_dec = (const float*)d_in[1];
  const float* enc_sproj_w = (const float*)d_in[2];
  const float* enc_sproj_b = (const float*)d_in[3];
  const float* enc_scproj_w = (const float*)d_in[4];
  const float* enc_scproj_b = (const float*)d_in[5];
  const float* enc_tok_w = (const float*)d_in[6];
  const float* enc_tok_b = (const float*)d_in[7];
  const float* dec_sproj_w = (const float*)d_in[8];
  const float* dec_sproj_b = (const float*)d_in[9];
  const float* dec_scproj_w = (const float*)d_in[10];
  const float* dec_scproj_b = (const float*)d_in[11];
  const float* dec_tok_w = (const float*)d_in[12];
  const float* dec_tok_b = (const float*)d_in[13];
  const float* e_Wq = (const float*)d_in[14];
  const float* e_bq = (const float*)d_in[15];
  const float* e_Wo = (const float*)d_in[16];
  const float* e_bo = (const float*)d_in[17];
  const float* e_c1w = (const float*)d_in[18];
  const float* e_c1b = (const float*)d_in[19];
  const float* e_c2w = (const float*)d_in[20];
  const float* e_c2b = (const float*)d_in[21];
  const float* e_ln1w = (const float*)d_in[22];
  const float* e_ln1b = (const float*)d_in[23];
  const float* e_ln2w = (const float*)d_in[24];
  const float* e_ln2b = (const float*)d_in[25];
  const float* enc_norm_w = (const float*)d_in[26];
  const float* enc_norm_b = (const float*)d_in[27];
  const float* d_sWq = (const float*)d_in[28];
  const float* d_sbq = (const float*)d_in[29];
  const float* d_sWo = (const float*)d_in[30];
  const float* d_sbo = (const float*)d_in[31];
  const float* d_cWq = (const float*)d_in[32];
  const float* d_cbq = (const float*)d_in[33];
  const float* d_cWo = (const float*)d_in[34];
  const float* d_cbo = (const float*)d_in[35];
  const float* d_c1w = (const float*)d_in[36];
  const float* d_c1b = (const float*)d_in[37];
  const float* d_c2w = (const float*)d_in[38];
  const float* d_c2b = (const float*)d_in[39];
  const float* d_ln1w = (const float*)d_in[40];
  const float* d_ln1b = (const float*)d_in[41];
  const float* d_ln2w = (const float*)d_in[42];
  const float* d_ln2b = (const float*)d_in[43];
  const float* d_ln3w = (const float*)d_in[44];
  const float* d_ln3b = (const float*)d_in[45];
  const float* dec_norm_w = (const float*)d_in[46];
  const float* dec_norm_b = (const float*)d_in[47];
  const float* proj_w = (const float*)d_in[48];
  const float* proj_b = (const float*)d_in[49];

  // ---- workspace layout ----
  const size_t ACT = 16777216;    // 65536*256
  const size_t POOLE = 4194304;   // 16384*256
  const size_t WBN = 3538944;     // bf16 weight pool elements
  size_t need = (3 * ACT + 2 * POOLE + WBN) * 2 +
                (size_t)(16384 + 147456 + 98304 + 65536) * 4;
  if (ws_size < need) {
    ws_signal<<<1, 1, 0, stream>>>((float*)d_out, (float)(ws_size >> 20));
    return;
  }
  char* wsb = (char*)d_ws;
  u16* A_enc = (u16*)wsb;  wsb += ACT * 2;
  u16* A_dec = (u16*)wsb;  wsb += ACT * 2;
  u16* T1 = (u16*)wsb;     wsb += ACT * 2;   // attn scratch; aliased as HF in FFN
  u16* PA = (u16*)wsb;     wsb += POOLE * 2;
  u16* PK = (u16*)wsb;     wsb += POOLE * 2;
  u16* WB = (u16*)wsb;     wsb += WBN * 2;
  float* PE = (float*)wsb;  wsb += 16384 * 4;
  float* EH1 = (float*)wsb; wsb += 147456 * 4;
  float* EH2 = (float*)wsb; wsb += 98304 * 4;
  float* EH3 = (float*)wsb; wsb += 65536 * 4;

  // bf16 weight pool offsets (elements)
  u16* eWq = WB;                    // 3 x 65536
  u16* eWeff = WB + 196608;         // 3 x 65536
  u16* eC1 = WB + 393216;           // 3 x 262144
  u16* eC2 = WB + 1179648;          // 3 x 262144
  u16* dB = WB + 1966080;
  u16* dsWq = dB;                   // 2 x 65536
  u16* dsWeff = dB + 131072;        // 2 x 65536
  u16* dcWq = dB + 262144;          // 2 x 65536
  u16* dcWeff = dB + 393216;        // 2 x 65536
  u16* dC1 = dB + 524288;           // 2 x 262144
  u16* dC2 = dB + 1048576;          // 2 x 262144

  // ---- weight conversion ----
  cvt_bf<<<768, 256, 0, stream>>>(e_Wq, eWq, 196608);
  cvt_bf<<<3072, 256, 0, stream>>>(e_c1w, eC1, 786432);
  cvt_bf<<<3072, 256, 0, stream>>>(e_c2w, eC2, 786432);
  cvt_bf<<<512, 256, 0, stream>>>(d_sWq, dsWq, 131072);
  cvt_bf<<<512, 256, 0, stream>>>(d_cWq, dcWq, 131072);
  cvt_bf<<<2048, 256, 0, stream>>>(d_c1w, dC1, 524288);
  cvt_bf<<<2048, 256, 0, stream>>>(d_c2w, dC2, 524288);
  for (int i = 0; i < 3; ++i)
    weff_bf<<<256, 256, 0, stream>>>(e_Wo + (size_t)i * 131072, eWeff + (size_t)i * 65536);
  for (int i = 0; i < 2; ++i) {
    weff_bf<<<256, 256, 0, stream>>>(d_sWo + (size_t)i * 131072, dsWeff + (size_t)i * 65536);
    weff_bf<<<256, 256, 0, stream>>>(d_cWo + (size_t)i * 131072, dcWeff + (size_t)i * 65536);
  }

  pe_kernel<<<64, 256, 0, stream>>>(PE);

  // ---- encoder embedding ----
  conv_sproj<<<dim3(96, 16), 96, 0, stream>>>(x_enc, enc_sproj_w, enc_sproj_b, EH1);
  conv_scproj_t<<<dim3(64, 16), 96, 0, stream>>>(EH1, enc_scproj_w, enc_scproj_b, EH2);
  conv_scproj_s<<<dim3(64, 16), 64, 0, stream>>>(EH2, enc_scproj_w, enc_scproj_b, EH3);
  tok_embed<<<1024, 256, 0, stream>>>(EH3, enc_tok_w, enc_tok_b, PE, A_enc);

  // ---- encoder layers ----
  for (int i = 0; i < 3; ++i) {
    mfma_gemm<0><<<dim3(2, 512), 256, 0, stream>>>(A_enc, eWq + (size_t)i * 65536,
                                                   e_bq + i * 256, T1, 256, 256);
    lin_attn<0, 0><<<1024, 512, 0, stream>>>(T1, nullptr);
    mfma_gemm_resln<<<512, 512, 0, stream>>>(T1, eWeff + (size_t)i * 65536, e_bo + i * 256,
                                             A_enc, e_ln1w + i * 256, e_ln1b + i * 256, 256);
    for (int c = 0; c < 4; ++c) {
      u16* Xc = A_enc + (size_t)c * 4194304;
      mfma_gemm<1><<<dim3(8, 128), 256, 0, stream>>>(Xc, eC1 + (size_t)i * 262144,
                                                     e_c1b + i * 1024, T1, 1024, 256);
      mfma_gemm_resln<<<128, 512, 0, stream>>>(T1, eC2 + (size_t)i * 262144, e_c2b + i * 256,
                                               Xc, e_ln2w + i * 256, e_ln2b + i * 256, 1024);
    }
  }
  ln_bf<<<16384, 256, 0, stream>>>(A_enc, enc_norm_w, enc_norm_b);
  pool_bf<<<16384, 256, 0, stream>>>(A_enc, PA);

  // ---- decoder embedding ----
  conv_sproj<<<dim3(96, 16), 96, 0, stream>>>(x_dec, dec_sproj_w, dec_sproj_b, EH1);
  conv_scproj_t<<<dim3(64, 16), 96, 0, stream>>>(EH1, dec_scproj_w, dec_scproj_b, EH2);
  conv_scproj_s<<<dim3(64, 16), 64, 0, stream>>>(EH2, dec_scproj_w, dec_scproj_b, EH3);
  tok_embed<<<1024, 256, 0, stream>>>(EH3, dec_tok_w, dec_tok_b, PE, A_dec);

  // ---- decoder layers ----
  for (int i = 0; i < 2; ++i) {
    mfma_gemm<0><<<dim3(2, 512), 256, 0, stream>>>(A_dec, dsWq + (size_t)i * 65536,
                                                   d_sbq + i * 256, T1, 256, 256);
    lin_attn<0, 1><<<1024, 512, 0, stream>>>(T1, nullptr);
    mfma_gemm_resln<<<512, 512, 0, stream>>>(T1, dsWeff + (size_t)i * 65536, d_sbo + i * 256,
                                             A_dec, d_ln1w + i * 256, d_ln1b + i * 256, 256);
    mfma_gemm<0><<<dim3(2, 512), 256, 0, stream>>>(A_dec, dcWq + (size_t)i * 65536,
                                                   d_cbq + i * 256, T1, 256, 256);
    mfma_gemm<0><<<dim3(2, 128), 256, 0, stream>>>(PA, dcWq + (size_t)i * 65536,
                                                   d_cbq + i * 256, PK, 256, 256);
    lin_attn<1, 0><<<1024, 512, 0, stream>>>(T1, PK);
    mfma_gemm_resln<<<512, 512, 0, stream>>>(T1, dcWeff + (size_t)i * 65536, d_cbo + i * 256,
                                             A_dec, d_ln2w + i * 256, d_ln2b + i * 256, 256);
    for (int c = 0; c < 4; ++c) {
      u16* Xc = A_dec + (size_t)c * 4194304;
      mfma_gemm<1><<<dim3(8, 128), 256, 0, stream>>>(Xc, dC1 + (size_t)i * 262144,
                                                     d_c1b + i * 1024, T1, 1024, 256);
      mfma_gemm_resln<<<128, 512, 0, stream>>>(T1, dC2 + (size_t)i * 262144, d_c2b + i * 256,
                                               Xc, d_ln3w + i * 256, d_ln3b + i * 256, 1024);
    }
  }
  ln_bf<<<16384, 256, 0, stream>>>(A_dec, dec_norm_w, dec_norm_b);

  mean_proj_bf<<<512, 256, 0, stream>>>(A_dec, proj_w, proj_b, (float*)d_out);
}

// Round 4
// 1822.230 us; speedup vs baseline: 3.9605x; 1.2693x over previous
//
#include <hip/hip_runtime.h>

// ---------------------------------------------------------------------------
// STLT forward. bf16 activations+weights, MFMA GEMMs (16x16x32 bf16), f32
// accum/epilogues. Activations flat (65536, 256) rows = (b, i, j).
// T==S==64 => qt==qs, kt==ks: Weff = Wo[:, :256] + Wo[:, 256:].
// R4: global_load_lds(16B) staging w/ pre-swizzled source; LDS-staged
// lin_attn; adaptive FFN hidden buffer.
// ---------------------------------------------------------------------------

typedef unsigned short u16;
typedef short s16;
typedef __attribute__((ext_vector_type(8))) s16 bfrag;   // 8 bf16 = 4 VGPR
typedef __attribute__((ext_vector_type(4))) float f32x4; // MFMA C/D

__device__ __forceinline__ float b2f(u16 u) {
  union { float f; unsigned int i; } v; v.i = ((unsigned int)u) << 16; return v.f;
}
__device__ __forceinline__ u16 f2b(float f) {
  union { float f; unsigned int i; } v; v.f = f;
  unsigned int x = v.i;
  return (u16)((x + 0x7FFFu + ((x >> 16) & 1u)) >> 16);
}

// async global->LDS, 16B per lane; LDS dest = base + lane*16 (wave-uniform base)
__device__ __forceinline__ void gload16(const void* g, void* l) {
  __builtin_amdgcn_global_load_lds(
      (const __attribute__((address_space(1))) unsigned int*)g,
      (__attribute__((address_space(3))) unsigned int*)l, 16, 0, 0);
}

__global__ void ws_signal(float* out, float v) { out[0] = v; }

// ---------------- weight conversion ----------------------------------------
__global__ void cvt_bf(const float* __restrict__ src, u16* __restrict__ dst, int n) {
  int i = blockIdx.x * 256 + threadIdx.x;
  if (i < n) dst[i] = f2b(src[i]);
}
__global__ void weff_bf(const float* __restrict__ Wo, u16* __restrict__ W) {
  int n = blockIdx.x, k = threadIdx.x;
  W[n * 256 + k] = f2b(Wo[n * 512 + k] + Wo[n * 512 + 256 + k]);
}

// ---------------- positional encoding --------------------------------------
__global__ void pe_kernel(float* __restrict__ pe) {
  int l = blockIdx.x, d = threadIdx.x;
  int i = d >> 1;
  float div = expf((float)(2 * i) * (-9.210340371976184f / 256.0f));
  float ang = (float)l * div;
  pe[l * 256 + d] = (d & 1) ? cosf(ang) : sinf(ang);
}

// ---------------- embedding convs (circular, K=3), f32 ---------------------
__global__ void conv_sproj(const float* __restrict__ x, const float* __restrict__ w,
                           const float* __restrict__ bias, float* __restrict__ h1) {
  int o = blockIdx.x, b = blockIdx.y, l = threadIdx.x;  // l < 96
  const float* wo = w + o * 192;
  const float* xb = x + (size_t)b * 96 * 64;
  float acc = bias[o];
#pragma unroll
  for (int k = 0; k < 3; ++k) {
    int lp = l + k - 1; if (lp < 0) lp += 96; if (lp >= 96) lp -= 96;
    const float* xr = xb + lp * 64;
    for (int c = 0; c < 64; ++c) acc = fmaf(xr[c], wo[c * 3 + k], acc);
  }
  h1[((size_t)b * 96 + o) * 96 + l] = acc;
}

__global__ void conv_scproj_t(const float* __restrict__ h1, const float* __restrict__ w,
                              const float* __restrict__ bias, float* __restrict__ h2) {
  int o = blockIdx.x, b = blockIdx.y, l = threadIdx.x;  // o<64, l<96
  const float* wo = w + o * 288;
  const float* hb = h1 + (size_t)b * 96 * 96;
  float acc = bias[o];
#pragma unroll
  for (int k = 0; k < 3; ++k) {
    int lp = l + k - 1; if (lp < 0) lp += 96; if (lp >= 96) lp -= 96;
    for (int c = 0; c < 96; ++c) acc = fmaf(hb[c * 96 + lp], wo[c * 3 + k], acc);
  }
  h2[((size_t)b * 64 + o) * 96 + l] = acc;
}

__global__ void conv_scproj_s(const float* __restrict__ h2, const float* __restrict__ w,
                              const float* __restrict__ bias, float* __restrict__ h3) {
  int o = blockIdx.x, b = blockIdx.y, l = threadIdx.x;  // o<64, l<64
  const float* wo = w + o * 288;
  const float* hb = h2 + (size_t)b * 64 * 96;
  float acc = bias[o];
#pragma unroll
  for (int k = 0; k < 3; ++k) {
    int lp = l + k - 1; if (lp < 0) lp += 64; if (lp >= 64) lp -= 64;
    for (int c = 0; c < 96; ++c) acc = fmaf(hb[lp * 96 + c], wo[c * 3 + k], acc);
  }
  h3[((size_t)b * 64 + o) * 64 + l] = acc;
}

__global__ void tok_embed(const float* __restrict__ h3, const float* __restrict__ w,
                          const float* __restrict__ bias, const float* __restrict__ pe,
                          u16* __restrict__ E) {
  int g = blockIdx.x, d = threadIdx.x;
  __shared__ float row[64];
  if (d < 64) row[d] = h3[(size_t)g * 64 + d];
  __syncthreads();
  float w0 = w[d * 3], w1 = w[d * 3 + 1], w2 = w[d * 3 + 2], bd = bias[d];
  for (int j = 0; j < 64; ++j) {
    int jm = (j + 63) & 63, jp = (j + 1) & 63;
    float v = bd + row[jm] * w0 + row[j] * w1 + row[jp] * w2 + pe[j * 256 + d];
    E[((size_t)g * 64 + j) * 256 + d] = f2b(v);
  }
}

// ---------------- MFMA GEMM: C(M,N) = A(M,K) @ W(N,K)^T + bias -------------
// 128x128 tile, 256 thr (4 waves 2x2). LDS fragment layout: wave-load wl
// holds global rows [wl*16, wl*16+16), kchunk (lane>>4)&3, at LDS wl*512+lane*8
// == exactly the 16x16x32 A/B fragment order. Staged via global_load_lds with
// pre-swizzled per-lane source addresses.
template <int ACT>
__global__ __launch_bounds__(256) void mfma_gemm(const u16* __restrict__ A,
                                                 const u16* __restrict__ W,
                                                 const float* __restrict__ bias,
                                                 u16* __restrict__ C, int N, int K) {
  __shared__ s16 As[4096];  // 128 rows x 32 k
  __shared__ s16 Bs[4096];
  int t = threadIdx.x;
  int wave = t >> 6, lane = t & 63;
  int wr = wave >> 1, wc = wave & 1;
  int row0 = blockIdx.y * 128, col0 = blockIdx.x * 128;
  int kc = (lane >> 4) & 3, rr = lane & 15;
  const u16* Ap0 = A + (size_t)(row0 + wave * 16 + rr) * K + kc * 8;
  const u16* Ap1 = A + (size_t)(row0 + (wave + 4) * 16 + rr) * K + kc * 8;
  const u16* Bp0 = W + (size_t)(col0 + wave * 16 + rr) * K + kc * 8;
  const u16* Bp1 = W + (size_t)(col0 + (wave + 4) * 16 + rr) * K + kc * 8;
  s16* lA0 = As + wave * 512;
  s16* lA1 = As + (wave + 4) * 512;
  s16* lB0 = Bs + wave * 512;
  s16* lB1 = Bs + (wave + 4) * 512;
  f32x4 acc[4][4];
#pragma unroll
  for (int m = 0; m < 4; ++m)
#pragma unroll
    for (int n = 0; n < 4; ++n) acc[m][n] = (f32x4){0.f, 0.f, 0.f, 0.f};
  for (int k0 = 0; k0 < K; k0 += 32) {
    gload16(Ap0 + k0, lA0);
    gload16(Ap1 + k0, lA1);
    gload16(Bp0 + k0, lB0);
    gload16(Bp1 + k0, lB1);
    __syncthreads();
    bfrag af[4], bf[4];
#pragma unroll
    for (int m = 0; m < 4; ++m) af[m] = *(const bfrag*)(As + ((wr * 4 + m) * 64 + lane) * 8);
#pragma unroll
    for (int n = 0; n < 4; ++n) bf[n] = *(const bfrag*)(Bs + ((wc * 4 + n) * 64 + lane) * 8);
#pragma unroll
    for (int m = 0; m < 4; ++m)
#pragma unroll
      for (int n = 0; n < 4; ++n)
        acc[m][n] = __builtin_amdgcn_mfma_f32_16x16x32_bf16(af[m], bf[n], acc[m][n], 0, 0, 0);
    __syncthreads();
  }
  int rbase = row0 + wr * 64 + ((lane >> 4) << 2);
  int cbase = col0 + wc * 64 + (lane & 15);
#pragma unroll
  for (int n = 0; n < 4; ++n) {
    int col = cbase + n * 16;
    float bcol = bias[col];
#pragma unroll
    for (int m = 0; m < 4; ++m) {
#pragma unroll
      for (int r = 0; r < 4; ++r) {
        float v = acc[m][n][r] + bcol;
        if (ACT == 1) v = 0.5f * v * (1.0f + erff(v * 0.7071067811865476f));
        C[(size_t)(rbase + m * 16 + r) * N + col] = f2b(v);
      }
    }
  }
}

// ---------------- MFMA GEMM + bias + residual + LayerNorm (N=256) ----------
// R(M,256) <- LN( X(M,K) @ W(256,K)^T + bias + R ). 128 rows/block, 512 thr.
__global__ __launch_bounds__(512) void mfma_gemm_resln(const u16* __restrict__ X,
                                                       const u16* __restrict__ W,
                                                       const float* __restrict__ bias,
                                                       u16* __restrict__ R,
                                                       const float* __restrict__ lnw,
                                                       const float* __restrict__ lnb,
                                                       int K) {
  __shared__ s16 As[4096];   // 128 rows x 32 k
  __shared__ s16 Bs[8192];   // 256 rows x 32 k
  __shared__ float pls[128][4][2];
  int t = threadIdx.x;
  int wave = t >> 6, lane = t & 63;
  int wr = wave >> 2, wc = wave & 3;
  int row0 = blockIdx.x * 128;
  int kc = (lane >> 4) & 3, rr = lane & 15;
  const u16* Xp = X + (size_t)(row0 + wave * 16 + rr) * K + kc * 8;
  const u16* Wp0 = W + (size_t)(wave * 16 + rr) * K + kc * 8;
  const u16* Wp1 = W + (size_t)((wave + 8) * 16 + rr) * K + kc * 8;
  s16* lA = As + wave * 512;
  s16* lB0 = Bs + wave * 512;
  s16* lB1 = Bs + (wave + 8) * 512;
  f32x4 acc[4][4];
#pragma unroll
  for (int m = 0; m < 4; ++m)
#pragma unroll
    for (int n = 0; n < 4; ++n) acc[m][n] = (f32x4){0.f, 0.f, 0.f, 0.f};
  for (int k0 = 0; k0 < K; k0 += 32) {
    gload16(Xp + k0, lA);
    gload16(Wp0 + k0, lB0);
    gload16(Wp1 + k0, lB1);
    __syncthreads();
    bfrag af[4], bf[4];
#pragma unroll
    for (int m = 0; m < 4; ++m) af[m] = *(const bfrag*)(As + ((wr * 4 + m) * 64 + lane) * 8);
#pragma unroll
    for (int n = 0; n < 4; ++n) bf[n] = *(const bfrag*)(Bs + ((wc * 4 + n) * 64 + lane) * 8);
#pragma unroll
    for (int m = 0; m < 4; ++m)
#pragma unroll
      for (int n = 0; n < 4; ++n)
        acc[m][n] = __builtin_amdgcn_mfma_f32_16x16x32_bf16(af[m], bf[n], acc[m][n], 0, 0, 0);
    __syncthreads();
  }
  // epilogue: bias + residual, then row LN across the 4 wc-waves
  int g4 = (lane >> 4) << 2;
  int cl = lane & 15;
  float lw[4], lb[4], bc[4];
#pragma unroll
  for (int n = 0; n < 4; ++n) {
    int col = wc * 64 + n * 16 + cl;
    bc[n] = bias[col]; lw[n] = lnw[col]; lb[n] = lnb[col];
  }
#pragma unroll
  for (int m = 0; m < 4; ++m) {
#pragma unroll
    for (int r = 0; r < 4; ++r) {
      int row = row0 + wr * 64 + m * 16 + g4 + r;
      float s = 0.f, s2 = 0.f;
#pragma unroll
      for (int n = 0; n < 4; ++n) {
        int col = wc * 64 + n * 16 + cl;
        float v = acc[m][n][r] + bc[n] + b2f(R[(size_t)row * 256 + col]);
        acc[m][n][r] = v;
        s += v; s2 = fmaf(v, v, s2);
      }
#pragma unroll
      for (int o = 1; o < 16; o <<= 1) { s += __shfl_xor(s, o); s2 += __shfl_xor(s2, o); }
      if (cl == 0) {
        int rl = wr * 64 + m * 16 + g4 + r;
        pls[rl][wc][0] = s; pls[rl][wc][1] = s2;
      }
    }
  }
  __syncthreads();
#pragma unroll
  for (int m = 0; m < 4; ++m) {
#pragma unroll
    for (int r = 0; r < 4; ++r) {
      int rl = wr * 64 + m * 16 + g4 + r;
      float s = pls[rl][0][0] + pls[rl][1][0] + pls[rl][2][0] + pls[rl][3][0];
      float s2 = pls[rl][0][1] + pls[rl][1][1] + pls[rl][2][1] + pls[rl][3][1];
      float mu = s * (1.0f / 256.0f);
      float var = fmaxf(s2 * (1.0f / 256.0f) - mu * mu, 0.0f);
      float rs = rsqrtf(var + 1e-5f);
      int row = row0 + wr * 64 + m * 16 + g4 + r;
#pragma unroll
      for (int n = 0; n < 4; ++n) {
        int col = wc * 64 + n * 16 + cl;
        R[(size_t)row * 256 + col] = f2b((acc[m][n][r] - mu) * rs * lw[n] + lb[n]);
      }
    }
  }
}

// ---------------- pooled linear attention (in-place on Q), LDS-staged ------
// Q tile (64x256) staged to LDS with coalesced 16B copies; padded row stride
// 264 u16 to break bank alignment. Thread (wave h, lane l) owns (row l,
// head h): reads 64B of q from LDS, writes result back to same LDS region.
template <int CROSS, int CAUSAL>
__global__ __launch_bounds__(512) void lin_attn(u16* __restrict__ Q,
                                                const u16* __restrict__ KP) {
  __shared__ u16 qs[64 * 264];
  __shared__ float kpool[16][260];
  int p = blockIdx.x, t = threadIdx.x;
  u16* Qg = Q + (size_t)p * 16384;
#pragma unroll
  for (int i = 0; i < 4; ++i) {
    int idx = i * 512 + t;          // 2048 chunks of 16B
    int row = idx >> 5, slot = idx & 31;
    *(uint4*)(qs + row * 264 + slot * 8) = *(const uint4*)(Qg + row * 256 + slot * 8);
  }
  __syncthreads();
  if (CROSS) {
    for (int idx = t; idx < 4096; idx += 512) {
      int s = idx >> 8, d = idx & 255;
      kpool[s][d] = b2f(KP[((size_t)p * 16 + s) * 256 + d]);
    }
  } else {
    for (int idx = t; idx < 4096; idx += 512) {
      int s = idx >> 8, d = idx & 255;
      const u16* b0 = qs + (4 * s) * 264 + d;
      kpool[s][d] = 0.25f * (b2f(b0[0]) + b2f(b0[264]) + b2f(b0[528]) + b2f(b0[792]));
    }
  }
  __syncthreads();
  int h = t >> 6, l = t & 63;
  u16* q = qs + l * 264 + h * 32;
  float qr[32];
#pragma unroll
  for (int e = 0; e < 32; e += 4) {
    ushort4 v = *(const ushort4*)&q[e];
    qr[e] = b2f(v.x); qr[e + 1] = b2f(v.y); qr[e + 2] = b2f(v.z); qr[e + 3] = b2f(v.w);
  }
  float sc[16], mx = -INFINITY;
#pragma unroll
  for (int s = 0; s < 16; ++s) {
    const float* kp = &kpool[s][h * 32];
    float d = 0.f;
#pragma unroll
    for (int e = 0; e < 32; ++e) d = fmaf(qr[e], kp[e], d);
    d *= 0.17677669529663687f;
    if (CAUSAL && s > l) d = -INFINITY;
    sc[s] = d; mx = fmaxf(mx, d);
  }
  float sum = 0.f;
#pragma unroll
  for (int s = 0; s < 16; ++s) { sc[s] = expf(sc[s] - mx); sum += sc[s]; }
  float inv = 1.0f / sum;
  float o[32] = {};
#pragma unroll
  for (int s = 0; s < 16; ++s) {
    float a = sc[s] * inv;
    const float* vp = &kpool[s][h * 32];
#pragma unroll
    for (int e = 0; e < 32; ++e) o[e] = fmaf(a, vp[e], o[e]);
  }
#pragma unroll
  for (int e = 0; e < 32; e += 4) {
    ushort4 v;
    v.x = f2b(o[e]); v.y = f2b(o[e + 1]); v.z = f2b(o[e + 2]); v.w = f2b(o[e + 3]);
    *(ushort4*)&q[e] = v;   // own region only: safe pre-barrier
  }
  __syncthreads();
#pragma unroll
  for (int i = 0; i < 4; ++i) {
    int idx = i * 512 + t;
    int row = idx >> 5, slot = idx & 31;
    *(uint4*)(Qg + row * 256 + slot * 8) = *(const uint4*)(qs + row * 264 + slot * 8);
  }
}

// ---------------- plain LayerNorm (in place), bf16 -------------------------
__global__ __launch_bounds__(256) void ln_bf(u16* __restrict__ X,
                                             const float* __restrict__ w,
                                             const float* __restrict__ b) {
  int lane = threadIdx.x & 63, wv = threadIdx.x >> 6;
  size_t row = (size_t)blockIdx.x * 4 + wv;
  size_t off = row * 256 + lane * 4;
  ushort4 xv = *(const ushort4*)(X + off);
  float v0 = b2f(xv.x), v1 = b2f(xv.y), v2 = b2f(xv.z), v3 = b2f(xv.w);
  float s = v0 + v1 + v2 + v3;
  float s2 = v0 * v0 + v1 * v1 + v2 * v2 + v3 * v3;
#pragma unroll
  for (int o = 32; o; o >>= 1) { s += __shfl_xor(s, o); s2 += __shfl_xor(s2, o); }
  float mu = s * (1.0f / 256.0f);
  float var = fmaxf(s2 * (1.0f / 256.0f) - mu * mu, 0.0f);
  float rs = rsqrtf(var + 1e-5f);
  float4 w4 = *(const float4*)(w + lane * 4);
  float4 b4 = *(const float4*)(b + lane * 4);
  ushort4 o4;
  o4.x = f2b((v0 - mu) * rs * w4.x + b4.x);
  o4.y = f2b((v1 - mu) * rs * w4.y + b4.y);
  o4.z = f2b((v2 - mu) * rs * w4.z + b4.z);
  o4.w = f2b((v3 - mu) * rs * w4.w + b4.w);
  *(ushort4*)(X + off) = o4;
}

// ---------------- pool over j (4:1) ----------------------------------------
__global__ void pool_bf(const u16* __restrict__ A, u16* __restrict__ P) {
  int r = blockIdx.x, d = threadIdx.x;
  int g = r >> 4, s = r & 15;
  const u16* src = A + ((size_t)g * 64 + 4 * (size_t)s) * 256 + d;
  float v = 0.25f * (b2f(src[0]) + b2f(src[256]) + b2f(src[512]) + b2f(src[768]));
  P[(size_t)r * 256 + d] = f2b(v);
}

// ---------------- mean over j + final projection + slice -------------------
__global__ __launch_bounds__(256) void mean_proj_bf(const u16* __restrict__ X,
                                                    const float* __restrict__ pw,
                                                    const float* __restrict__ pb,
                                                    float* __restrict__ out) {
  int bid = blockIdx.x;
  int b = bid >> 5, ii = bid & 31;
  int i = 32 + ii;
  __shared__ float md[256];
  int d = threadIdx.x;
  const u16* base = X + ((size_t)b * 64 + i) * 64 * 256 + d;
  float s = 0.f;
  for (int j = 0; j < 64; ++j) s += b2f(base[(size_t)j * 256]);
  md[d] = s * (1.0f / 64.0f);
  __syncthreads();
  if (d < 64) {
    float acc = pb[d];
    const float* wr = pw + d * 256;
    for (int k = 0; k < 256; ++k) acc = fmaf(md[k], wr[k], acc);
    out[((size_t)b * 32 + ii) * 64 + d] = acc;
  }
}

// ---------------------------------------------------------------------------
extern "C" void kernel_launch(void* const* d_in, const int* in_sizes, int n_in,
                              void* d_out, int out_size, void* d_ws, size_t ws_size,
                              hipStream_t stream) {
  (void)in_sizes; (void)out_size;
  if (n_in < 50) return;

  const float* x_enc = (const float*)d_in[0];
  const float* x_dec = (const float*)d_in[1];
  const float* enc_sproj_w = (const float*)d_in[2];
  const float* enc_sproj_b = (const float*)d_in[3];
  const float* enc_scproj_w = (const float*)d_in[4];
  const float* enc_scproj_b = (const float*)d_in[5];
  const float* enc_tok_w = (const float*)d_in[6];
  const float* enc_tok_b = (const float*)d_in[7];
  const float* dec_sproj_w = (const float*)d_in[8];
  const float* dec_sproj_b = (const float*)d_in[9];
  const float* dec_scproj_w = (const float*)d_in[10];
  const float* dec_scproj_b = (const float*)d_in[11];
  const float* dec_tok_w = (const float*)d_in[12];
  const float* dec_tok_b = (const float*)d_in[13];
  const float* e_Wq = (const float*)d_in[14];
  const float* e_bq = (const float*)d_in[15];
  const float* e_Wo = (const float*)d_in[16];
  const float* e_bo = (const float*)d_in[17];
  const float* e_c1w = (const float*)d_in[18];
  const float* e_c1b = (const float*)d_in[19];
  const float* e_c2w = (const float*)d_in[20];
  const float* e_c2b = (const float*)d_in[21];
  const float* e_ln1w = (const float*)d_in[22];
  const float* e_ln1b = (const float*)d_in[23];
  const float* e_ln2w = (const float*)d_in[24];
  const float* e_ln2b = (const float*)d_in[25];
  const float* enc_norm_w = (const float*)d_in[26];
  const float* enc_norm_b = (const float*)d_in[27];
  const float* d_sWq = (const float*)d_in[28];
  const float* d_sbq = (const float*)d_in[29];
  const float* d_sWo = (const float*)d_in[30];
  const float* d_sbo = (const float*)d_in[31];
  const float* d_cWq = (const float*)d_in[32];
  const float* d_cbq = (const float*)d_in[33];
  const float* d_cWo = (const float*)d_in[34];
  const float* d_cbo = (const float*)d_in[35];
  const float* d_c1w = (const float*)d_in[36];
  const float* d_c1b = (const float*)d_in[37];
  const float* d_c2w = (const float*)d_in[38];
  const float* d_c2b = (const float*)d_in[39];
  const float* d_ln1w = (const float*)d_in[40];
  const float* d_ln1b = (const float*)d_in[41];
  const float* d_ln2w = (const float*)d_in[42];
  const float* d_ln2b = (const float*)d_in[43];
  const float* d_ln3w = (const float*)d_in[44];
  const float* d_ln3b = (const float*)d_in[45];
  const float* dec_norm_w = (const float*)d_in[46];
  const float* dec_norm_b = (const float*)d_in[47];
  const float* proj_w = (const float*)d_in[48];
  const float* proj_b = (const float*)d_in[49];

  // ---- workspace layout ----
  const size_t ACT = 16777216;    // 65536*256
  const size_t POOLE = 4194304;   // 16384*256
  const size_t WBN = 3538944;     // bf16 weight pool elements
  size_t base_need = (3 * ACT + 2 * POOLE + WBN) * 2 +
                     (size_t)(16384 + 147456 + 98304 + 65536) * 4;
  if (ws_size < base_need) {
    ws_signal<<<1, 1, 0, stream>>>((float*)d_out, (float)(ws_size >> 20));
    return;
  }
  char* wsb = (char*)d_ws;
  u16* A_enc = (u16*)wsb;  wsb += ACT * 2;
  u16* A_dec = (u16*)wsb;  wsb += ACT * 2;
  u16* T1 = (u16*)wsb;     wsb += ACT * 2;   // attn scratch
  u16* PA = (u16*)wsb;     wsb += POOLE * 2;
  u16* PK = (u16*)wsb;     wsb += POOLE * 2;
  u16* WB = (u16*)wsb;     wsb += WBN * 2;
  float* PE = (float*)wsb;  wsb += 16384 * 4;
  float* EH1 = (float*)wsb; wsb += 147456 * 4;
  float* EH2 = (float*)wsb; wsb += 98304 * 4;
  float* EH3 = (float*)wsb; wsb += 65536 * 4;

  // adaptive FFN hidden buffer: prefer one full-width pass
  int hf_rows = 16384;
  u16* HF = T1;  // default: alias attn scratch (dead during FFN)
  if (ws_size >= base_need + (size_t)65536 * 1024 * 2) {
    hf_rows = 65536; HF = (u16*)wsb;
  } else if (ws_size >= base_need + (size_t)32768 * 1024 * 2) {
    hf_rows = 32768; HF = (u16*)wsb;
  }

  // bf16 weight pool offsets (elements)
  u16* eWq = WB;                    // 3 x 65536
  u16* eWeff = WB + 196608;         // 3 x 65536
  u16* eC1 = WB + 393216;           // 3 x 262144
  u16* eC2 = WB + 1179648;          // 3 x 262144
  u16* dB = WB + 1966080;
  u16* dsWq = dB;                   // 2 x 65536
  u16* dsWeff = dB + 131072;        // 2 x 65536
  u16* dcWq = dB + 262144;          // 2 x 65536
  u16* dcWeff = dB + 393216;        // 2 x 65536
  u16* dC1 = dB + 524288;           // 2 x 262144
  u16* dC2 = dB + 1048576;          // 2 x 262144

  // ---- weight conversion ----
  cvt_bf<<<768, 256, 0, stream>>>(e_Wq, eWq, 196608);
  cvt_bf<<<3072, 256, 0, stream>>>(e_c1w, eC1, 786432);
  cvt_bf<<<3072, 256, 0, stream>>>(e_c2w, eC2, 786432);
  cvt_bf<<<512, 256, 0, stream>>>(d_sWq, dsWq, 131072);
  cvt_bf<<<512, 256, 0, stream>>>(d_cWq, dcWq, 131072);
  cvt_bf<<<2048, 256, 0, stream>>>(d_c1w, dC1, 524288);
  cvt_bf<<<2048, 256, 0, stream>>>(d_c2w, dC2, 524288);
  for (int i = 0; i < 3; ++i)
    weff_bf<<<256, 256, 0, stream>>>(e_Wo + (size_t)i * 131072, eWeff + (size_t)i * 65536);
  for (int i = 0; i < 2; ++i) {
    weff_bf<<<256, 256, 0, stream>>>(d_sWo + (size_t)i * 131072, dsWeff + (size_t)i * 65536);
    weff_bf<<<256, 256, 0, stream>>>(d_cWo + (size_t)i * 131072, dcWeff + (size_t)i * 65536);
  }

  pe_kernel<<<64, 256, 0, stream>>>(PE);

  // ---- encoder embedding ----
  conv_sproj<<<dim3(96, 16), 96, 0, stream>>>(x_enc, enc_sproj_w, enc_sproj_b, EH1);
  conv_scproj_t<<<dim3(64, 16), 96, 0, stream>>>(EH1, enc_scproj_w, enc_scproj_b, EH2);
  conv_scproj_s<<<dim3(64, 16), 64, 0, stream>>>(EH2, enc_scproj_w, enc_scproj_b, EH3);
  tok_embed<<<1024, 256, 0, stream>>>(EH3, enc_tok_w, enc_tok_b, PE, A_enc);

  // ---- encoder layers ----
  for (int i = 0; i < 3; ++i) {
    mfma_gemm<0><<<dim3(2, 512), 256, 0, stream>>>(A_enc, eWq + (size_t)i * 65536,
                                                   e_bq + i * 256, T1, 256, 256);
    lin_attn<0, 0><<<1024, 512, 0, stream>>>(T1, nullptr);
    mfma_gemm_resln<<<512, 512, 0, stream>>>(T1, eWeff + (size_t)i * 65536, e_bo + i * 256,
                                             A_enc, e_ln1w + i * 256, e_ln1b + i * 256, 256);
    for (int m0 = 0; m0 < 65536; m0 += hf_rows) {
      u16* Xc = A_enc + (size_t)m0 * 256;
      mfma_gemm<1><<<dim3(8, hf_rows / 128), 256, 0, stream>>>(
          Xc, eC1 + (size_t)i * 262144, e_c1b + i * 1024, HF, 1024, 256);
      mfma_gemm_resln<<<hf_rows / 128, 512, 0, stream>>>(
          HF, eC2 + (size_t)i * 262144, e_c2b + i * 256, Xc,
          e_ln2w + i * 256, e_ln2b + i * 256, 1024);
    }
  }
  ln_bf<<<16384, 256, 0, stream>>>(A_enc, enc_norm_w, enc_norm_b);
  pool_bf<<<16384, 256, 0, stream>>>(A_enc, PA);

  // ---- decoder embedding ----
  conv_sproj<<<dim3(96, 16), 96, 0, stream>>>(x_dec, dec_sproj_w, dec_sproj_b, EH1);
  conv_scproj_t<<<dim3(64, 16), 96, 0, stream>>>(EH1, dec_scproj_w, dec_scproj_b, EH2);
  conv_scproj_s<<<dim3(64, 16), 64, 0, stream>>>(EH2, dec_scproj_w, dec_scproj_b, EH3);
  tok_embed<<<1024, 256, 0, stream>>>(EH3, dec_tok_w, dec_tok_b, PE, A_dec);

  // ---- decoder layers ----
  for (int i = 0; i < 2; ++i) {
    mfma_gemm<0><<<dim3(2, 512), 256, 0, stream>>>(A_dec, dsWq + (size_t)i * 65536,
                                                   d_sbq + i * 256, T1, 256, 256);
    lin_attn<0, 1><<<1024, 512, 0, stream>>>(T1, nullptr);
    mfma_gemm_resln<<<512, 512, 0, stream>>>(T1, dsWeff + (size_t)i * 65536, d_sbo + i * 256,
                                             A_dec, d_ln1w + i * 256, d_ln1b + i * 256, 256);
    mfma_gemm<0><<<dim3(2, 512), 256, 0, stream>>>(A_dec, dcWq + (size_t)i * 65536,
                                                   d_cbq + i * 256, T1, 256, 256);
    mfma_gemm<0><<<dim3(2, 128), 256, 0, stream>>>(PA, dcWq + (size_t)i * 65536,
                                                   d_cbq + i * 256, PK, 256, 256);
    lin_attn<1, 0><<<1024, 512, 0, stream>>>(T1, PK);
    mfma_gemm_resln<<<512, 512, 0, stream>>>(T1, dcWeff + (size_t)i * 65536, d_cbo + i * 256,
                                             A_dec, d_ln2w + i * 256, d_ln2b + i * 256, 256);
    for (int m0 = 0; m0 < 65536; m0 += hf_rows) {
      u16* Xc = A_dec + (size_t)m0 * 256;
      mfma_gemm<1><<<dim3(8, hf_rows / 128), 256, 0, stream>>>(
          Xc, dC1 + (size_t)i * 262144, d_c1b + i * 1024, HF, 1024, 256);
      mfma_gemm_resln<<<hf_rows / 128, 512, 0, stream>>>(
          HF, dC2 + (size_t)i * 262144, d_c2b + i * 256, Xc,
          d_ln3w + i * 256, d_ln3b + i * 256, 1024);
    }
  }
  ln_bf<<<16384, 256, 0, stream>>>(A_dec, dec_norm_w, dec_norm_b);

  mean_proj_bf<<<512, 256, 0, stream>>>(A_dec, proj_w, proj_b, (float*)d_out);
}